// Round 6
// baseline (147.226 us; speedup 1.0000x reference)
//
#include <hip/hip_runtime.h>
#include <math.h>

// OneClassLoss: BS=128, HW=128. x1,x2: (128,1,128,128) fp32. Output: scalar fp32.
//
// ws layout (floats) — every region fully overwritten each launch:
//   [0,256)              na[0..128)|nb[0..128)   (ocl_finish norm branch)
//   [256,16640)          G[i*128+j] final Gram   (ocl_finish gram branch)
//   [16640,18688)        NP[img*8+wave] norm partials (ocl_main fft branch)
//   [20736,4215040)      Gp[ks][16384] partial Gram slabs (ocl_main gram branch)
//   [4215040,6344960)    P[img][8320] per-image PSD (ocl_main fft branch)
//   [6344960,6345025)    PS[k], [6345025,6345090) PL[k]  (ocl_finish)
//   [6345090]            completion counter (int; zeroed by ocl_main block 0)

#define WS_N     0
#define WS_G     256
#define WS_NP    16640
#define WS_GP    20736
#define WS_P     4215040
#define WS_PS    6344960
#define WS_PL    6345025
#define WS_CNT   6345090

#define PI_F 3.14159265358979323846f

// ---------------- Register/shuffle 128-pt complex FFT (DIF, bit-reversed out) --
__device__ __forceinline__ void fft128_reg(float& s0r, float& s0i,
                                           float& s1r, float& s1i,
                                           float cA, float sA,
                                           const float* wr, const float* wi,
                                           int lane) {
    float er = s0r + s1r, ei = s0i + s1i;
    float dr = s0r - s1r, di = s0i - s1i;
    float orr = dr * cA - di * sA;
    float oii = dr * sA + di * cA;
    #pragma unroll
    for (int st = 0; st < 6; ++st) {
        int m = 32 >> st;
        bool up = (lane & m) == 0;
        float tr = __shfl_xor(er, m), ti = __shfl_xor(ei, m);
        float ar = tr - er, ai = ti - ei;
        float e2r = up ? (er + tr) : (ar * wr[st] - ai * wi[st]);
        float e2i = up ? (ei + ti) : (ar * wi[st] + ai * wr[st]);
        tr = __shfl_xor(orr, m); ti = __shfl_xor(oii, m);
        float br_ = tr - orr, bi_ = ti - oii;
        float o2r = up ? (orr + tr) : (br_ * wr[st] - bi_ * wi[st]);
        float o2i = up ? (oii + ti) : (br_ * wi[st] + bi_ * wr[st]);
        er = e2r; ei = e2i; orr = o2r; oii = o2i;
    }
    s0r = er; s0i = ei; s1r = orr; s1i = oii;
}

// ---------------- Kernel 1: merged gram (blocks 0..255) + fft (256..511) -------
// 512 threads, 64 KB LDS union -> 2 blocks/CU; gram (VALU) overlaps fft (DS).
__global__ __launch_bounds__(512) void ocl_main(const float* __restrict__ x1,
                                                const float* __restrict__ x2,
                                                float* __restrict__ ws) {
    __shared__ float4 smem4[4096];     // 64 KB union
    int t = threadIdx.x;
    int bid = blockIdx.x;

    if (bid < 256) {
        // ================= GRAM: K-split ks, K-chunk 64 =================
        if (bid == 0 && t == 0) *((int*)(ws + WS_CNT)) = 0;
        float4* As = smem4;            // [128][16] float4, XOR-swizzled
        float4* Bs = smem4 + 2048;
        int ks = bid, k0q = ks * 16;
        const float4* A = (const float4*)x1;
        const float4* B = (const float4*)x2;
        {
            int qi = t & 15, r0 = t >> 4;
            #pragma unroll
            for (int p = 0; p < 4; ++p) {
                int r = r0 + 32 * p;
                int sq = qi ^ ((r >> 3) & 7);
                As[r * 16 + sq] = A[(size_t)r * 4096 + k0q + qi];
                Bs[r * 16 + sq] = B[(size_t)r * 4096 + k0q + qi];
            }
        }
        __syncthreads();

        int ty = t >> 4, tx = t & 15;  // rows ty*4.., cols tx*8..
        float acc[4][8];
        #pragma unroll
        for (int r = 0; r < 4; ++r)
            #pragma unroll
            for (int c = 0; c < 8; ++c) acc[r][c] = 0.0f;

        for (int qk = 0; qk < 16; ++qk) {
            float4 a4[4], b4[8];
            #pragma unroll
            for (int r = 0; r < 4; ++r) {
                int rr = ty * 4 + r;
                a4[r] = As[rr * 16 + (qk ^ ((rr >> 3) & 7))];
            }
            #pragma unroll
            for (int c = 0; c < 8; ++c) {
                int rc = tx * 8 + c;
                b4[c] = Bs[rc * 16 + (qk ^ ((rc >> 3) & 7))];
            }
            #pragma unroll
            for (int r = 0; r < 4; ++r)
                #pragma unroll
                for (int c = 0; c < 8; ++c) {
                    float4 a = a4[r], b = b4[c];
                    acc[r][c] = fmaf(a.x, b.x, fmaf(a.y, b.y,
                                fmaf(a.z, b.z, fmaf(a.w, b.w, acc[r][c]))));
                }
        }

        float4* Gq = (float4*)(ws + WS_GP + (size_t)ks * 16384);
        #pragma unroll
        for (int r = 0; r < 4; ++r)
            #pragma unroll
            for (int cc = 0; cc < 2; ++cc)
                Gq[(ty * 4 + r) * 32 + tx * 2 + cc] =
                    make_float4(acc[r][cc * 4 + 0], acc[r][cc * 4 + 1],
                                acc[r][cc * 4 + 2], acc[r][cc * 4 + 3]);
    } else {
        // ================= FFT + PSD + norm partials =================
        float* zre = (float*)smem4;
        float* zim = zre + 8192;
        int lane = t & 63, wave = t >> 6;   // 8 waves
        int img = bid - 256;
        float* P = ws + WS_P + (size_t)img * 8320;
        const float* src = (img < 128) ? (x1 + (size_t)img * 16384)
                                       : (x2 + (size_t)(img - 128) * 16384);

        float cA, sA, wr[6], wi[6];
        {
            float th = -PI_F * (float)lane / 64.0f;
            sA = __sinf(th); cA = __cosf(th);
            #pragma unroll
            for (int st = 0; st < 6; ++st) {
                int m = 32 >> st;
                float a = -PI_F * (float)(lane & (m - 1)) / (float)m;
                wi[st] = __sinf(a); wr[st] = __cosf(a);
            }
        }
        int rb = (int)(__brev((unsigned)lane) >> 26);  // br6(lane)

        // Row phase: 8 packed row-pair FFTs per wave; fused ||x||^2
        float nrm = 0.0f;
        #pragma unroll
        for (int pi = 0; pi < 8; ++pi) {
            int p = wave * 8 + pi;
            const float* r0 = src + p * 256 + lane;
            float s0r = r0[0],   s1r = r0[64];
            float s0i = r0[128], s1i = r0[192];
            nrm += s0r * s0r + s1r * s1r + s0i * s0i + s1i * s1i;
            fft128_reg(s0r, s0i, s1r, s1i, cA, sA, wr, wi, lane);
            int f0 = (2 * rb + p) & 127;
            int f1 = (2 * rb + 1 + p) & 127;
            zre[p * 128 + f0] = s0r; zim[p * 128 + f0] = s0i;
            zre[p * 128 + f1] = s1r; zim[p * 128 + f1] = s1i;
        }
        for (int off = 32; off >= 1; off >>= 1) nrm += __shfl_xor(nrm, off);
        if (lane == 0) ws[WS_NP + img * 8 + wave] = nrm;
        __syncthreads();

        // Column phase: 65 column FFTs (k=0..64) over 8 waves
        int p0 = (lane >> 1), p1 = 32 + (lane >> 1);
        int par = lane & 1;
        for (int k = wave; k < 65; k += 8) {
            float v0r, v0i, v1r, v1i;
            if (k == 0 || k == 64) {
                int c0 = (k + p0) & 127, c1 = (k + p1) & 127;
                float Z0r = zre[p0 * 128 + c0], Z0i = zim[p0 * 128 + c0];
                float Z1r = zre[p1 * 128 + c1], Z1i = zim[p1 * 128 + c1];
                v0r = par ? Z0i : Z0r; v0i = 0.0f;
                v1r = par ? Z1i : Z1r; v1i = 0.0f;
            } else {
                int kn = 128 - k;
                int ck = (k + p0) & 127, cn = (kn + p0) & 127;
                float Zkr = zre[p0 * 128 + ck], Zki = zim[p0 * 128 + ck];
                float Znr = zre[p0 * 128 + cn], Zni = zim[p0 * 128 + cn];
                float e0r = 0.5f * (Zkr + Znr), e0i = 0.5f * (Zki - Zni);
                float q0r = 0.5f * (Zki + Zni), q0i = 0.5f * (Znr - Zkr);
                v0r = par ? q0r : e0r; v0i = par ? q0i : e0i;
                ck = (k + p1) & 127; cn = (kn + p1) & 127;
                Zkr = zre[p1 * 128 + ck]; Zki = zim[p1 * 128 + ck];
                Znr = zre[p1 * 128 + cn]; Zni = zim[p1 * 128 + cn];
                float e1r = 0.5f * (Zkr + Znr), e1i = 0.5f * (Zki - Zni);
                float q1r = 0.5f * (Zki + Zni), q1i = 0.5f * (Znr - Zkr);
                v1r = par ? q1r : e1r; v1i = par ? q1i : e1i;
            }
            fft128_reg(v0r, v0i, v1r, v1i, cA, sA, wr, wi, lane);
            P[k * 128 + lane]      = v0r * v0r + v0i * v0i;
            P[k * 128 + 64 + lane] = v1r * v1r + v1i * v1i;
        }
    }
}

// ---------------- Kernel 2: reductions + last-block tail (grid 322) ------------
// blocks [0,256): Gram partial sum (block g owns floats [g*64,(g+1)*64))
// blocks [256,321): PSD column k=bid-256 -> PS[k], PL[k]
// block 321: norm partials -> na/nb
// The LAST block (device-scope counter) computes the final scalar.
__global__ __launch_bounds__(256) void ocl_finish(float* __restrict__ ws,
                                                  float* __restrict__ out) {
    int bid = blockIdx.x, t = threadIdx.x;
    int lane = t & 63, wave = t >> 6;
    __shared__ float4 sh4[256];

    if (bid < 256) {
        int g = bid;
        const float4* Gp4 = (const float4*)(ws + WS_GP);
        int qi = t & 15, sg = t >> 4;          // 16 quads x 16 slab-groups
        float4 acc = make_float4(0.f, 0.f, 0.f, 0.f);
        #pragma unroll 4
        for (int it = 0; it < 16; ++it) {
            int sl = sg * 16 + it;
            float4 v = Gp4[(size_t)sl * 4096 + g * 16 + qi];
            acc.x += v.x; acc.y += v.y; acc.z += v.z; acc.w += v.w;
        }
        sh4[t] = acc;
        __syncthreads();
        if (t < 16) {
            float4 s = sh4[t];
            #pragma unroll
            for (int sg2 = 1; sg2 < 16; ++sg2) {
                float4 v = sh4[sg2 * 16 + t];
                s.x += v.x; s.y += v.y; s.z += v.z; s.w += v.w;
            }
            ((float4*)(ws + WS_G))[g * 16 + t] = s;
        }
    } else if (bid < 321) {
        int k = bid - 256;
        const float4* P4 = (const float4*)(ws + WS_P);
        int u4 = t & 31, ig = t >> 5;          // 32 quads x 8 image-groups
        float4 acc = make_float4(0.f, 0.f, 0.f, 0.f);
        #pragma unroll 4
        for (int it = 0; it < 32; ++it) {
            int im = ig * 32 + it;
            float4 v = P4[(size_t)im * 2080 + k * 32 + u4];
            acc.x += v.x; acc.y += v.y; acc.z += v.z; acc.w += v.w;
        }
        sh4[t] = acc;
        __syncthreads();
        float sS = 0.0f, sL = 0.0f;
        if (t < 32) {
            float4 s = sh4[t];
            #pragma unroll
            for (int ig2 = 1; ig2 < 8; ++ig2) {
                float4 v = sh4[ig2 * 32 + t];
                s.x += v.x; s.y += v.y; s.z += v.z; s.w += v.w;
            }
            float w = (k == 0 || k == 64) ? 1.0f : 2.0f;
            sS = w * (s.x + s.y + s.z + s.w);
            sL = w * (logf(s.x) + logf(s.y) + logf(s.z) + logf(s.w));
        }
        #pragma unroll
        for (int off = 16; off >= 1; off >>= 1) {
            sS += __shfl_xor(sS, off);
            sL += __shfl_xor(sL, off);
        }
        if (t == 0) {
            ws[WS_PS + k] = sS;
            ws[WS_PL + k] = sL;
        }
    } else {
        const float* NP = ws + WS_NP + t * 8;
        float s = 0.0f;
        #pragma unroll
        for (int w = 0; w < 8; ++w) s += NP[w];
        ws[WS_N + t] = s;
    }

    // ---- completion: last block computes the final scalar ----
    __threadfence();
    __shared__ int lastflag;
    if (t == 0) {
        int old = atomicAdd((int*)(ws + WS_CNT), 1);
        lastflag = (old == 321) ? 1 : 0;
    }
    __syncthreads();
    if (!lastflag) return;
    __threadfence();

    const float* na = ws + WS_N;
    const float* nb = ws + WS_N + 128;
    const float* G  = ws + WS_G;
    float rowacc = 0.0f;
    for (int ri = 0; ri < 32; ++ri) {
        int i = wave * 32 + ri;
        int j0 = lane, j1 = 64 + lane;
        size_t b = (size_t)i * 128;
        float d0 = sqrtf(fmaxf(na[i] + nb[j0] - 2.0f * G[b + j0], 0.0f));
        float d1 = sqrtf(fmaxf(na[i] + nb[j1] - 2.0f * G[b + j1], 0.0f));
        float mx = fmaxf(d0, d1);
        for (int off = 32; off >= 1; off >>= 1) mx = fmaxf(mx, __shfl_xor(mx, off));
        float sm = expf(d0 - mx) + expf(d1 - mx);
        for (int off = 32; off >= 1; off >>= 1) sm += __shfl_xor(sm, off);
        float dii = (i < 64) ? __shfl(d0, i) : __shfl(d1, i - 64);
        rowacc += mx + logf(sm) - dii;     // identical on all lanes
    }

    float sS = 0.0f, sL = 0.0f;
    if (t < 65) { sS = ws[WS_PS + t]; sL = ws[WS_PL + t]; }
    for (int off = 32; off >= 1; off >>= 1) {
        sS += __shfl_xor(sS, off);
        sL += __shfl_xor(sL, off);
    }
    __shared__ float aS[4], aL[4], aR[4];
    if (lane == 0) { aS[wave] = sS; aL[wave] = sL; aR[wave] = rowacc; }
    __syncthreads();
    if (t == 0) {
        float S_ = aS[0] + aS[1] + aS[2] + aS[3];
        float L_ = aL[0] + aL[1] + aL[2] + aL[3];
        float R_ = aR[0] + aR[1] + aR[2] + aR[3];
        float ce = R_ / 128.0f;
        float r  = L_ / 16384.0f - logf(S_ / 16384.0f);
        out[0] = ce - 0.1f * r;
    }
}

extern "C" void kernel_launch(void* const* d_in, const int* in_sizes, int n_in,
                              void* d_out, int out_size, void* d_ws, size_t ws_size,
                              hipStream_t stream) {
    (void)in_sizes; (void)n_in; (void)out_size; (void)ws_size;
    const float* x1 = (const float*)d_in[0];
    const float* x2 = (const float*)d_in[1];
    float* ws  = (float*)d_ws;
    float* out = (float*)d_out;

    hipLaunchKernelGGL(ocl_main,   dim3(512), dim3(512), 0, stream, x1, x2, ws);
    hipLaunchKernelGGL(ocl_finish, dim3(322), dim3(256), 0, stream, ws, out);
}

// Round 7
// 128.256 us; speedup vs baseline: 1.1479x; 1.1479x over previous
//
#include <hip/hip_runtime.h>
#include <math.h>

// OneClassLoss: BS=128, HW=128. x1,x2: (128,1,128,128) fp32. Output: scalar fp32.
//
// ws layout (floats):
//   [0,256)             na[0..128)|nb[0..128)  (atomicAdd from fft blocks; poison
//                       base 0xAA = -2.4e-13, negligible)
//   [256,16640)         D[i*128+j] distances   (finish gram-D blocks)
//   [20736,4215040)     Gp4[e16*1024+ks*4+q] interleaved Gram partials (main)
//   [4215040,6344960)   P[bin16*4096+img*16+m] interleaved PSD partials (main)
//   [6344960,6345025)   PS[k];  [6345025,6345090) PL[k]   (finish PSD blocks)
//   [6345090]           completion counter (zeroed by main block 0)

#define WS_N     0
#define WS_D     256
#define WS_GP    20736
#define WS_P     4215040
#define WS_PS    6344960
#define WS_PL    6345025
#define WS_CNT   6345090

#define PI_F 3.14159265358979323846f

// ---------------- Register/shuffle 128-pt complex FFT (DIF, bit-reversed out) --
__device__ __forceinline__ void fft128_reg(float& s0r, float& s0i,
                                           float& s1r, float& s1i,
                                           float cA, float sA,
                                           const float* wr, const float* wi,
                                           int lane) {
    float er = s0r + s1r, ei = s0i + s1i;
    float dr = s0r - s1r, di = s0i - s1i;
    float orr = dr * cA - di * sA;
    float oii = dr * sA + di * cA;
    #pragma unroll
    for (int st = 0; st < 6; ++st) {
        int m = 32 >> st;
        bool up = (lane & m) == 0;
        float tr = __shfl_xor(er, m), ti = __shfl_xor(ei, m);
        float ar = tr - er, ai = ti - ei;
        float e2r = up ? (er + tr) : (ar * wr[st] - ai * wi[st]);
        float e2i = up ? (ei + ti) : (ar * wi[st] + ai * wr[st]);
        tr = __shfl_xor(orr, m); ti = __shfl_xor(oii, m);
        float br_ = tr - orr, bi_ = ti - oii;
        float o2r = up ? (orr + tr) : (br_ * wr[st] - bi_ * wi[st]);
        float o2i = up ? (oii + ti) : (br_ * wi[st] + bi_ * wr[st]);
        er = e2r; ei = e2i; orr = o2r; oii = o2i;
    }
    s0r = er; s0i = ei; s1r = orr; s1i = oii;
}

// ---------------- Kernel 1: merged gram (blocks 0..255) + fft (256..511) -------
__global__ __launch_bounds__(512) void ocl_main(const float* __restrict__ x1,
                                                const float* __restrict__ x2,
                                                float* __restrict__ ws) {
    __shared__ float4 smem4[4096];     // 64 KB union
    int t = threadIdx.x;
    int bid = blockIdx.x;

    if (bid < 256) {
        // ================= GRAM K-split ks (K-chunk 64) =================
        if (bid == 0 && t == 0) *((int*)(ws + WS_CNT)) = 0;
        float4* As = smem4;            // [128][16] float4, XOR-swizzled
        float4* Bs = smem4 + 2048;
        int ks = bid, k0q = ks * 16;
        const float4* A = (const float4*)x1;
        const float4* B = (const float4*)x2;
        {
            int qi = t & 15, r0 = t >> 4;
            #pragma unroll
            for (int p = 0; p < 4; ++p) {
                int r = r0 + 32 * p;
                int sq = qi ^ ((r >> 3) & 7);
                As[r * 16 + sq] = A[(size_t)r * 4096 + k0q + qi];
                Bs[r * 16 + sq] = B[(size_t)r * 4096 + k0q + qi];
            }
        }
        __syncthreads();

        int ty = t >> 4, tx = t & 15;  // rows ty*4.., col-quads tx*2..
        float acc[4][8];
        #pragma unroll
        for (int r = 0; r < 4; ++r)
            #pragma unroll
            for (int c = 0; c < 8; ++c) acc[r][c] = 0.0f;

        for (int qk = 0; qk < 16; ++qk) {
            float4 a4[4], b4[8];
            #pragma unroll
            for (int r = 0; r < 4; ++r) {
                int rr = ty * 4 + r;
                a4[r] = As[rr * 16 + (qk ^ ((rr >> 3) & 7))];
            }
            #pragma unroll
            for (int c = 0; c < 8; ++c) {
                int rc = tx * 8 + c;
                b4[c] = Bs[rc * 16 + (qk ^ ((rc >> 3) & 7))];
            }
            #pragma unroll
            for (int r = 0; r < 4; ++r)
                #pragma unroll
                for (int c = 0; c < 8; ++c) {
                    float4 a = a4[r], b = b4[c];
                    acc[r][c] = fmaf(a.x, b.x, fmaf(a.y, b.y,
                                fmaf(a.z, b.z, fmaf(a.w, b.w, acc[r][c]))));
                }
        }

        // Interleaved store: Gp4[e16*1024 + ks*4 + q], e4 = row*32 + (tx*2+cc)
        float4* Gp4 = (float4*)(ws + WS_GP);
        #pragma unroll
        for (int r = 0; r < 4; ++r)
            #pragma unroll
            for (int cc = 0; cc < 2; ++cc) {
                int e4 = (ty * 4 + r) * 32 + tx * 2 + cc;
                Gp4[(size_t)(e4 >> 2) * 1024 + ks * 4 + (e4 & 3)] =
                    make_float4(acc[r][cc * 4 + 0], acc[r][cc * 4 + 1],
                                acc[r][cc * 4 + 2], acc[r][cc * 4 + 3]);
            }
    } else {
        // ================= FFT + PSD + norms =================
        float* zre = (float*)smem4;
        float* zim = zre + 8192;
        int lane = t & 63, wave = t >> 6;   // 8 waves
        int img = bid - 256;
        const float* src = (img < 128) ? (x1 + (size_t)img * 16384)
                                       : (x2 + (size_t)(img - 128) * 16384);

        float cA, sA, wr[6], wi[6];
        {
            float th = -PI_F * (float)lane / 64.0f;
            sA = __sinf(th); cA = __cosf(th);
            #pragma unroll
            for (int st = 0; st < 6; ++st) {
                int m = 32 >> st;
                float a = -PI_F * (float)(lane & (m - 1)) / (float)m;
                wi[st] = __sinf(a); wr[st] = __cosf(a);
            }
        }
        int rb = (int)(__brev((unsigned)lane) >> 26);  // br6(lane)

        float nrm = 0.0f;
        #pragma unroll
        for (int pi = 0; pi < 8; ++pi) {
            int p = wave * 8 + pi;
            const float* r0 = src + p * 256 + lane;
            float s0r = r0[0],   s1r = r0[64];
            float s0i = r0[128], s1i = r0[192];
            nrm += s0r * s0r + s1r * s1r + s0i * s0i + s1i * s1i;
            fft128_reg(s0r, s0i, s1r, s1i, cA, sA, wr, wi, lane);
            int f0 = (2 * rb + p) & 127;
            int f1 = (2 * rb + 1 + p) & 127;
            zre[p * 128 + f0] = s0r; zim[p * 128 + f0] = s0i;
            zre[p * 128 + f1] = s1r; zim[p * 128 + f1] = s1i;
        }
        for (int off = 32; off >= 1; off >>= 1) nrm += __shfl_xor(nrm, off);
        if (lane == 0) atomicAdd(&ws[WS_N + img], nrm);  // 8 adds/image
        __syncthreads();

        int p0 = (lane >> 1), p1 = 32 + (lane >> 1);
        int par = lane & 1;
        float* P = ws + WS_P;
        for (int k = wave; k < 65; k += 8) {
            float v0r, v0i, v1r, v1i;
            if (k == 0 || k == 64) {
                int c0 = (k + p0) & 127, c1 = (k + p1) & 127;
                float Z0r = zre[p0 * 128 + c0], Z0i = zim[p0 * 128 + c0];
                float Z1r = zre[p1 * 128 + c1], Z1i = zim[p1 * 128 + c1];
                v0r = par ? Z0i : Z0r; v0i = 0.0f;
                v1r = par ? Z1i : Z1r; v1i = 0.0f;
            } else {
                int kn = 128 - k;
                int ck = (k + p0) & 127, cn = (kn + p0) & 127;
                float Zkr = zre[p0 * 128 + ck], Zki = zim[p0 * 128 + ck];
                float Znr = zre[p0 * 128 + cn], Zni = zim[p0 * 128 + cn];
                float e0r = 0.5f * (Zkr + Znr), e0i = 0.5f * (Zki - Zni);
                float q0r = 0.5f * (Zki + Zni), q0i = 0.5f * (Znr - Zkr);
                v0r = par ? q0r : e0r; v0i = par ? q0i : e0i;
                ck = (k + p1) & 127; cn = (kn + p1) & 127;
                Zkr = zre[p1 * 128 + ck]; Zki = zim[p1 * 128 + ck];
                Znr = zre[p1 * 128 + cn]; Zni = zim[p1 * 128 + cn];
                float e1r = 0.5f * (Zkr + Znr), e1i = 0.5f * (Zki - Zni);
                float q1r = 0.5f * (Zki + Zni), q1i = 0.5f * (Znr - Zkr);
                v1r = par ? q1r : e1r; v1i = par ? q1i : e1i;
            }
            fft128_reg(v0r, v0i, v1r, v1i, cA, sA, wr, wi, lane);
            // Interleaved: P[bin16*4096 + img*16 + m]; bin = k*128 + s*64 + lane
            int m = lane & 15, hi = lane >> 4;
            P[(size_t)(k * 8 + 0 + hi) * 4096 + img * 16 + m] = v0r * v0r + v0i * v0i;
            P[(size_t)(k * 8 + 4 + hi) * 4096 + img * 16 + m] = v1r * v1r + v1i * v1i;
        }
    }
}

// ---------------- Kernel 2: reductions + last-block tail (grid 321) ------------
// blocks [0,256): block g reads its private 64 KB Gp slice -> D (half-row g)
// blocks [256,321): PSD bins of column k=bid-256 -> PS[k], PL[k]
// last arriving block computes the final scalar.
__global__ __launch_bounds__(256) void ocl_finish(float* __restrict__ ws,
                                                  float* __restrict__ out) {
    int bid = blockIdx.x, t = threadIdx.x;
    int lane = t & 63, wave = t >> 6;

    if (bid < 256) {
        int g = bid;
        const float4* Gp4 = (const float4*)(ws + WS_GP);
        // thread: e16 = g*4+wave, q = (lane>>4)&3, kg = lane&15; 16 ks each
        int q = (lane >> 4) & 3, kg = lane & 15;
        const float4* base = Gp4 + (size_t)g * 4096 + wave * 1024 + q;
        float4 v[16];
        #pragma unroll
        for (int it = 0; it < 16; ++it) v[it] = base[(kg * 16 + it) * 4];
        float4 s = v[0];
        #pragma unroll
        for (int it = 1; it < 16; ++it) {
            s.x += v[it].x; s.y += v[it].y; s.z += v[it].z; s.w += v[it].w;
        }
        #pragma unroll
        for (int msk = 1; msk <= 8; msk <<= 1) {
            s.x += __shfl_xor(s.x, msk); s.y += __shfl_xor(s.y, msk);
            s.z += __shfl_xor(s.z, msk); s.w += __shfl_xor(s.w, msk);
        }
        if (kg == 0) {
            int i = g >> 1;
            float nai = ws[WS_N + i];
            float4 nb4 = ((const float4*)(ws + WS_N + 128))[(g & 1) * 16 + wave * 4 + q];
            float4 d;
            d.x = sqrtf(fmaxf(nai + nb4.x - 2.0f * s.x, 0.0f));
            d.y = sqrtf(fmaxf(nai + nb4.y - 2.0f * s.y, 0.0f));
            d.z = sqrtf(fmaxf(nai + nb4.z - 2.0f * s.z, 0.0f));
            d.w = sqrtf(fmaxf(nai + nb4.w - 2.0f * s.w, 0.0f));
            ((float4*)(ws + WS_D))[i * 32 + (g & 1) * 16 + wave * 4 + q] = d;
        }
    } else {
        int k = bid - 256;
        const float4* P4 = (const float4*)(ws + WS_P);
        // thread: bin16_l = t>>5, m4 = (t>>3)&3, hq = t&7; 32 imgs each
        int b16 = t >> 5, m4 = (t >> 3) & 3, hq = t & 7;
        const float4* base = P4 + (size_t)(k * 8 + b16) * 1024 + m4;
        float4 s = make_float4(0.f, 0.f, 0.f, 0.f);
        #pragma unroll
        for (int half = 0; half < 2; ++half) {
            float4 u[16];
            #pragma unroll
            for (int it = 0; it < 16; ++it)
                u[it] = base[(hq * 32 + half * 16 + it) * 4];
            #pragma unroll
            for (int it = 0; it < 16; ++it) {
                s.x += u[it].x; s.y += u[it].y; s.z += u[it].z; s.w += u[it].w;
            }
        }
        #pragma unroll
        for (int msk = 1; msk <= 4; msk <<= 1) {
            s.x += __shfl_xor(s.x, msk); s.y += __shfl_xor(s.y, msk);
            s.z += __shfl_xor(s.z, msk); s.w += __shfl_xor(s.w, msk);
        }
        float sS = 0.0f, sL = 0.0f;
        if (hq == 0) {
            float w = (k == 0 || k == 64) ? 1.0f : 2.0f;
            sS = w * (s.x + s.y + s.z + s.w);
            sL = w * (logf(s.x) + logf(s.y) + logf(s.z) + logf(s.w));
        }
        #pragma unroll
        for (int off = 32; off >= 1; off >>= 1) {
            sS += __shfl_xor(sS, off);
            sL += __shfl_xor(sL, off);
        }
        __shared__ float aS[4], aL[4];
        if (lane == 0) { aS[wave] = sS; aL[wave] = sL; }
        __syncthreads();
        if (t == 0) {
            ws[WS_PS + k] = aS[0] + aS[1] + aS[2] + aS[3];
            ws[WS_PL + k] = aL[0] + aL[1] + aL[2] + aL[3];
        }
    }

    // ---- completion: last block computes the final scalar ----
    __threadfence();
    __shared__ int lastflag;
    if (t == 0) {
        int old = atomicAdd((int*)(ws + WS_CNT), 1);
        lastflag = (old == 320) ? 1 : 0;
    }
    __syncthreads();
    if (!lastflag) return;
    __threadfence();

    // LSE: 2 threads per row; 16 independent float4 loads up-front.
    int i = t >> 1, h = t & 1;
    const float4* D4 = (const float4*)(ws + WS_D);
    float4 dv[16];
    #pragma unroll
    for (int it = 0; it < 16; ++it) dv[it] = D4[i * 32 + h * 16 + it];
    float mx = -1.0f;
    #pragma unroll
    for (int it = 0; it < 16; ++it)
        mx = fmaxf(mx, fmaxf(fmaxf(dv[it].x, dv[it].y), fmaxf(dv[it].z, dv[it].w)));
    float mo = __shfl_xor(mx, 1);
    float m2 = fmaxf(mx, mo);
    float sm = 0.0f;
    #pragma unroll
    for (int it = 0; it < 16; ++it)
        sm += __expf(dv[it].x - m2) + __expf(dv[it].y - m2) +
              __expf(dv[it].z - m2) + __expf(dv[it].w - m2);
    sm += __shfl_xor(sm, 1);
    float dii = 0.0f;
    if ((i >> 6) == h) {
        int lc = i & 63;
        float4 dq = dv[lc >> 2];
        dii = (i & 2) ? ((i & 1) ? dq.w : dq.z) : ((i & 1) ? dq.y : dq.x);
    }
    dii += __shfl_xor(dii, 1);
    float rowacc = 0.5f * (m2 + logf(sm) - dii);   // each row counted twice

    float sS = 0.0f, sL = 0.0f;
    if (t < 65) { sS = ws[WS_PS + t]; sL = ws[WS_PL + t]; }
    #pragma unroll
    for (int off = 32; off >= 1; off >>= 1) {
        sS += __shfl_xor(sS, off);
        sL += __shfl_xor(sL, off);
        rowacc += __shfl_xor(rowacc, off);
    }
    __shared__ float bS[4], bL[4], bR[4];
    if (lane == 0) { bS[wave] = sS; bL[wave] = sL; bR[wave] = rowacc; }
    __syncthreads();
    if (t == 0) {
        float S_ = bS[0] + bS[1] + bS[2] + bS[3];
        float L_ = bL[0] + bL[1] + bL[2] + bL[3];
        float R_ = bR[0] + bR[1] + bR[2] + bR[3];
        float ce = R_ / 128.0f;
        float r  = L_ / 16384.0f - logf(S_ / 16384.0f);
        out[0] = ce - 0.1f * r;
    }
}

extern "C" void kernel_launch(void* const* d_in, const int* in_sizes, int n_in,
                              void* d_out, int out_size, void* d_ws, size_t ws_size,
                              hipStream_t stream) {
    (void)in_sizes; (void)n_in; (void)out_size; (void)ws_size;
    const float* x1 = (const float*)d_in[0];
    const float* x2 = (const float*)d_in[1];
    float* ws  = (float*)d_ws;
    float* out = (float*)d_out;

    hipLaunchKernelGGL(ocl_main,   dim3(512), dim3(512), 0, stream, x1, x2, ws);
    hipLaunchKernelGGL(ocl_finish, dim3(321), dim3(256), 0, stream, ws, out);
}

// Round 8
// 100.297 us; speedup vs baseline: 1.4679x; 1.2788x over previous
//
#include <hip/hip_runtime.h>
#include <math.h>

// OneClassLoss: BS=128, HW=128. x1,x2: (128,1,128,128) fp32. Output: scalar fp32.
//
// ws layout (floats):
//   [0,256)             na[0..128)|nb[0..128)  (atomicAdd from fft blocks; poison
//                       base 0xAA = -3.0e-13, negligible vs ~16384)
//   [256,16640)         D[i*128+j] distances   (ocl_finish gram-D blocks)
//   [20736,4215040)     Gp4[e16*1024+ks*4+q] interleaved Gram partials (main)
//   [4215040,6344960)   P[bin16*4096+img*16+m] interleaved PSD partials (main)
//   [6344960,6345025)   PS[k];  [6345025,6345090) PL[k]   (ocl_finish PSD blocks)

#define WS_N     0
#define WS_D     256
#define WS_GP    20736
#define WS_P     4215040
#define WS_PS    6344960
#define WS_PL    6345025

#define PI_F 3.14159265358979323846f

// ---------------- Register/shuffle 128-pt complex FFT (DIF, bit-reversed out) --
__device__ __forceinline__ void fft128_reg(float& s0r, float& s0i,
                                           float& s1r, float& s1i,
                                           float cA, float sA,
                                           const float* wr, const float* wi,
                                           int lane) {
    float er = s0r + s1r, ei = s0i + s1i;
    float dr = s0r - s1r, di = s0i - s1i;
    float orr = dr * cA - di * sA;
    float oii = dr * sA + di * cA;
    #pragma unroll
    for (int st = 0; st < 6; ++st) {
        int m = 32 >> st;
        bool up = (lane & m) == 0;
        float tr = __shfl_xor(er, m), ti = __shfl_xor(ei, m);
        float ar = tr - er, ai = ti - ei;
        float e2r = up ? (er + tr) : (ar * wr[st] - ai * wi[st]);
        float e2i = up ? (ei + ti) : (ar * wi[st] + ai * wr[st]);
        tr = __shfl_xor(orr, m); ti = __shfl_xor(oii, m);
        float br_ = tr - orr, bi_ = ti - oii;
        float o2r = up ? (orr + tr) : (br_ * wr[st] - bi_ * wi[st]);
        float o2i = up ? (oii + ti) : (br_ * wi[st] + bi_ * wr[st]);
        er = e2r; ei = e2i; orr = o2r; oii = o2i;
    }
    s0r = er; s0i = ei; s1r = orr; s1i = oii;
}

// ---------------- Kernel 1: merged gram (blocks 0..255) + fft (256..511) -------
__global__ __launch_bounds__(512) void ocl_main(const float* __restrict__ x1,
                                                const float* __restrict__ x2,
                                                float* __restrict__ ws) {
    __shared__ float4 smem4[4096];     // 64 KB union
    int t = threadIdx.x;
    int bid = blockIdx.x;

    if (bid < 256) {
        // ================= GRAM K-split ks (K-chunk 64) =================
        float4* As = smem4;            // [128][16] float4, XOR-swizzled
        float4* Bs = smem4 + 2048;
        int ks = bid, k0q = ks * 16;
        const float4* A = (const float4*)x1;
        const float4* B = (const float4*)x2;
        {
            int qi = t & 15, r0 = t >> 4;
            #pragma unroll
            for (int p = 0; p < 4; ++p) {
                int r = r0 + 32 * p;
                int sq = qi ^ ((r >> 3) & 7);
                As[r * 16 + sq] = A[(size_t)r * 4096 + k0q + qi];
                Bs[r * 16 + sq] = B[(size_t)r * 4096 + k0q + qi];
            }
        }
        __syncthreads();

        int ty = t >> 4, tx = t & 15;  // rows ty*4.., col-quads tx*2..
        float acc[4][8];
        #pragma unroll
        for (int r = 0; r < 4; ++r)
            #pragma unroll
            for (int c = 0; c < 8; ++c) acc[r][c] = 0.0f;

        for (int qk = 0; qk < 16; ++qk) {
            float4 a4[4], b4[8];
            #pragma unroll
            for (int r = 0; r < 4; ++r) {
                int rr = ty * 4 + r;
                a4[r] = As[rr * 16 + (qk ^ ((rr >> 3) & 7))];
            }
            #pragma unroll
            for (int c = 0; c < 8; ++c) {
                int rc = tx * 8 + c;
                b4[c] = Bs[rc * 16 + (qk ^ ((rc >> 3) & 7))];
            }
            #pragma unroll
            for (int r = 0; r < 4; ++r)
                #pragma unroll
                for (int c = 0; c < 8; ++c) {
                    float4 a = a4[r], b = b4[c];
                    acc[r][c] = fmaf(a.x, b.x, fmaf(a.y, b.y,
                                fmaf(a.z, b.z, fmaf(a.w, b.w, acc[r][c]))));
                }
        }

        // Interleaved store: Gp4[e16*1024 + ks*4 + q], e4 = row*32 + (tx*2+cc)
        float4* Gp4 = (float4*)(ws + WS_GP);
        #pragma unroll
        for (int r = 0; r < 4; ++r)
            #pragma unroll
            for (int cc = 0; cc < 2; ++cc) {
                int e4 = (ty * 4 + r) * 32 + tx * 2 + cc;
                Gp4[(size_t)(e4 >> 2) * 1024 + ks * 4 + (e4 & 3)] =
                    make_float4(acc[r][cc * 4 + 0], acc[r][cc * 4 + 1],
                                acc[r][cc * 4 + 2], acc[r][cc * 4 + 3]);
            }
    } else {
        // ================= FFT + PSD + norms =================
        float* zre = (float*)smem4;
        float* zim = zre + 8192;
        int lane = t & 63, wave = t >> 6;   // 8 waves
        int img = bid - 256;
        const float* src = (img < 128) ? (x1 + (size_t)img * 16384)
                                       : (x2 + (size_t)(img - 128) * 16384);

        float cA, sA, wr[6], wi[6];
        {
            float th = -PI_F * (float)lane / 64.0f;
            sA = __sinf(th); cA = __cosf(th);
            #pragma unroll
            for (int st = 0; st < 6; ++st) {
                int m = 32 >> st;
                float a = -PI_F * (float)(lane & (m - 1)) / (float)m;
                wi[st] = __sinf(a); wr[st] = __cosf(a);
            }
        }
        int rb = (int)(__brev((unsigned)lane) >> 26);  // br6(lane)

        float nrm = 0.0f;
        #pragma unroll
        for (int pi = 0; pi < 8; ++pi) {
            int p = wave * 8 + pi;
            const float* r0 = src + p * 256 + lane;
            float s0r = r0[0],   s1r = r0[64];
            float s0i = r0[128], s1i = r0[192];
            nrm += s0r * s0r + s1r * s1r + s0i * s0i + s1i * s1i;
            fft128_reg(s0r, s0i, s1r, s1i, cA, sA, wr, wi, lane);
            int f0 = (2 * rb + p) & 127;
            int f1 = (2 * rb + 1 + p) & 127;
            zre[p * 128 + f0] = s0r; zim[p * 128 + f0] = s0i;
            zre[p * 128 + f1] = s1r; zim[p * 128 + f1] = s1i;
        }
        for (int off = 32; off >= 1; off >>= 1) nrm += __shfl_xor(nrm, off);
        if (lane == 0) atomicAdd(&ws[WS_N + img], nrm);  // 8 adds/image
        __syncthreads();

        int p0 = (lane >> 1), p1 = 32 + (lane >> 1);
        int par = lane & 1;
        float* P = ws + WS_P;
        for (int k = wave; k < 65; k += 8) {
            float v0r, v0i, v1r, v1i;
            if (k == 0 || k == 64) {
                int c0 = (k + p0) & 127, c1 = (k + p1) & 127;
                float Z0r = zre[p0 * 128 + c0], Z0i = zim[p0 * 128 + c0];
                float Z1r = zre[p1 * 128 + c1], Z1i = zim[p1 * 128 + c1];
                v0r = par ? Z0i : Z0r; v0i = 0.0f;
                v1r = par ? Z1i : Z1r; v1i = 0.0f;
            } else {
                int kn = 128 - k;
                int ck = (k + p0) & 127, cn = (kn + p0) & 127;
                float Zkr = zre[p0 * 128 + ck], Zki = zim[p0 * 128 + ck];
                float Znr = zre[p0 * 128 + cn], Zni = zim[p0 * 128 + cn];
                float e0r = 0.5f * (Zkr + Znr), e0i = 0.5f * (Zki - Zni);
                float q0r = 0.5f * (Zki + Zni), q0i = 0.5f * (Znr - Zkr);
                v0r = par ? q0r : e0r; v0i = par ? q0i : e0i;
                ck = (k + p1) & 127; cn = (kn + p1) & 127;
                Zkr = zre[p1 * 128 + ck]; Zki = zim[p1 * 128 + ck];
                Znr = zre[p1 * 128 + cn]; Zni = zim[p1 * 128 + cn];
                float e1r = 0.5f * (Zkr + Znr), e1i = 0.5f * (Zki - Zni);
                float q1r = 0.5f * (Zki + Zni), q1i = 0.5f * (Znr - Zkr);
                v1r = par ? q1r : e1r; v1i = par ? q1i : e1i;
            }
            fft128_reg(v0r, v0i, v1r, v1i, cA, sA, wr, wi, lane);
            // Interleaved: P[bin16*4096 + img*16 + m]; bin = k*128 + s*64 + lane
            int m = lane & 15, hi = lane >> 4;
            P[(size_t)(k * 8 + 0 + hi) * 4096 + img * 16 + m] = v0r * v0r + v0i * v0i;
            P[(size_t)(k * 8 + 4 + hi) * 4096 + img * 16 + m] = v1r * v1r + v1i * v1i;
        }
    }
}

// ---------------- Kernel 2: reductions (grid 321), no fences -------------------
// blocks [0,256): block g reads its private contiguous 64 KB Gp slice -> D
// blocks [256,321): PSD bins of column k=bid-256 -> PS[k], PL[k]
__global__ __launch_bounds__(256) void ocl_finish(float* __restrict__ ws) {
    int bid = blockIdx.x, t = threadIdx.x;
    int lane = t & 63, wave = t >> 6;

    if (bid < 256) {
        int g = bid;
        const float4* Gp4 = (const float4*)(ws + WS_GP);
        int q = (lane >> 4) & 3, kg = lane & 15;
        const float4* base = Gp4 + (size_t)g * 4096 + wave * 1024 + q;
        float4 v[16];
        #pragma unroll
        for (int it = 0; it < 16; ++it) v[it] = base[(kg * 16 + it) * 4];
        float4 s = v[0];
        #pragma unroll
        for (int it = 1; it < 16; ++it) {
            s.x += v[it].x; s.y += v[it].y; s.z += v[it].z; s.w += v[it].w;
        }
        #pragma unroll
        for (int msk = 1; msk <= 8; msk <<= 1) {
            s.x += __shfl_xor(s.x, msk); s.y += __shfl_xor(s.y, msk);
            s.z += __shfl_xor(s.z, msk); s.w += __shfl_xor(s.w, msk);
        }
        if (kg == 0) {
            int i = g >> 1;
            float nai = ws[WS_N + i];
            float4 nb4 = ((const float4*)(ws + WS_N + 128))[(g & 1) * 16 + wave * 4 + q];
            float4 d;
            d.x = sqrtf(fmaxf(nai + nb4.x - 2.0f * s.x, 0.0f));
            d.y = sqrtf(fmaxf(nai + nb4.y - 2.0f * s.y, 0.0f));
            d.z = sqrtf(fmaxf(nai + nb4.z - 2.0f * s.z, 0.0f));
            d.w = sqrtf(fmaxf(nai + nb4.w - 2.0f * s.w, 0.0f));
            ((float4*)(ws + WS_D))[i * 32 + (g & 1) * 16 + wave * 4 + q] = d;
        }
    } else {
        int k = bid - 256;
        const float4* P4 = (const float4*)(ws + WS_P);
        int b16 = t >> 5, m4 = (t >> 3) & 3, hq = t & 7;
        const float4* base = P4 + (size_t)(k * 8 + b16) * 1024 + m4;
        float4 s = make_float4(0.f, 0.f, 0.f, 0.f);
        #pragma unroll
        for (int half = 0; half < 2; ++half) {
            float4 u[16];
            #pragma unroll
            for (int it = 0; it < 16; ++it)
                u[it] = base[(hq * 32 + half * 16 + it) * 4];
            #pragma unroll
            for (int it = 0; it < 16; ++it) {
                s.x += u[it].x; s.y += u[it].y; s.z += u[it].z; s.w += u[it].w;
            }
        }
        #pragma unroll
        for (int msk = 1; msk <= 4; msk <<= 1) {
            s.x += __shfl_xor(s.x, msk); s.y += __shfl_xor(s.y, msk);
            s.z += __shfl_xor(s.z, msk); s.w += __shfl_xor(s.w, msk);
        }
        float sS = 0.0f, sL = 0.0f;
        if (hq == 0) {
            float w = (k == 0 || k == 64) ? 1.0f : 2.0f;
            sS = w * (s.x + s.y + s.z + s.w);
            sL = w * (logf(s.x) + logf(s.y) + logf(s.z) + logf(s.w));
        }
        #pragma unroll
        for (int off = 32; off >= 1; off >>= 1) {
            sS += __shfl_xor(sS, off);
            sL += __shfl_xor(sL, off);
        }
        __shared__ float aS[4], aL[4];
        if (lane == 0) { aS[wave] = sS; aL[wave] = sL; }
        __syncthreads();
        if (t == 0) {
            ws[WS_PS + k] = aS[0] + aS[1] + aS[2] + aS[3];
            ws[WS_PL + k] = aL[0] + aL[1] + aL[2] + aL[3];
        }
    }
}

// ---------------- Kernel 3: tail — 1 block, LSE + PSD pairs -> scalar ----------
__global__ __launch_bounds__(256) void ocl_tail(const float* __restrict__ ws,
                                                float* __restrict__ out) {
    int t = threadIdx.x, lane = t & 63, wave = t >> 6;

    // LSE: 2 threads per row; 16 independent float4 loads up-front.
    int i = t >> 1, h = t & 1;
    const float4* D4 = (const float4*)(ws + WS_D);
    float4 dv[16];
    #pragma unroll
    for (int it = 0; it < 16; ++it) dv[it] = D4[i * 32 + h * 16 + it];
    float mx = -1.0f;
    #pragma unroll
    for (int it = 0; it < 16; ++it)
        mx = fmaxf(mx, fmaxf(fmaxf(dv[it].x, dv[it].y), fmaxf(dv[it].z, dv[it].w)));
    float mo = __shfl_xor(mx, 1);
    float m2 = fmaxf(mx, mo);
    float sm = 0.0f;
    #pragma unroll
    for (int it = 0; it < 16; ++it)
        sm += __expf(dv[it].x - m2) + __expf(dv[it].y - m2) +
              __expf(dv[it].z - m2) + __expf(dv[it].w - m2);
    sm += __shfl_xor(sm, 1);
    float dii = 0.0f;
    if ((i >> 6) == h) {
        int lc = i & 63;
        float4 dq = dv[lc >> 2];
        dii = (i & 2) ? ((i & 1) ? dq.w : dq.z) : ((i & 1) ? dq.y : dq.x);
    }
    dii += __shfl_xor(dii, 1);
    float rowacc = 0.5f * (m2 + logf(sm) - dii);   // each row counted twice

    float sS = 0.0f, sL = 0.0f;
    if (t < 65) { sS = ws[WS_PS + t]; sL = ws[WS_PL + t]; }
    #pragma unroll
    for (int off = 32; off >= 1; off >>= 1) {
        sS += __shfl_xor(sS, off);
        sL += __shfl_xor(sL, off);
        rowacc += __shfl_xor(rowacc, off);
    }
    __shared__ float bS[4], bL[4], bR[4];
    if (lane == 0) { bS[wave] = sS; bL[wave] = sL; bR[wave] = rowacc; }
    __syncthreads();
    if (t == 0) {
        float S_ = bS[0] + bS[1] + bS[2] + bS[3];
        float L_ = bL[0] + bL[1] + bL[2] + bL[3];
        float R_ = bR[0] + bR[1] + bR[2] + bR[3];
        float ce = R_ / 128.0f;
        float r  = L_ / 16384.0f - logf(S_ / 16384.0f);
        out[0] = ce - 0.1f * r;
    }
}

extern "C" void kernel_launch(void* const* d_in, const int* in_sizes, int n_in,
                              void* d_out, int out_size, void* d_ws, size_t ws_size,
                              hipStream_t stream) {
    (void)in_sizes; (void)n_in; (void)out_size; (void)ws_size;
    const float* x1 = (const float*)d_in[0];
    const float* x2 = (const float*)d_in[1];
    float* ws  = (float*)d_ws;
    float* out = (float*)d_out;

    hipLaunchKernelGGL(ocl_main,   dim3(512), dim3(512), 0, stream, x1, x2, ws);
    hipLaunchKernelGGL(ocl_finish, dim3(321), dim3(256), 0, stream, ws);
    hipLaunchKernelGGL(ocl_tail,   dim3(1),   dim3(256), 0, stream, ws, out);
}

// Round 9
// 94.284 us; speedup vs baseline: 1.5615x; 1.0638x over previous
//
#include <hip/hip_runtime.h>
#include <math.h>

// OneClassLoss: BS=128, HW=128. x1,x2: (128,1,128,128) fp32. Output: scalar fp32.
//
// ws layout (floats) — every region fully overwritten each launch (poison-proof):
//   [256,512)           Se[g]  = sum_j exp(D[g-half-row] - Mx[g])   (finish)
//   [512,768)           Mx[g]  = local max of D over half-row g     (finish)
//   [768,896)           Dii[i] = D[i][i]                            (finish)
//   [16640,18688)       NP[img*8+wave] norm partials                (main fft)
//   [20736,4215040)     Gp4[e16*1024+ks*4+q] interleaved Gram partials (main)
//   [4215040,6344960)   P[bin16*4096+img*16+m] interleaved PSD partials (main)
//   [6344960,6345025)   PS[k];  [6345025,6345090) PL[k]             (finish)

#define WS_SE    256
#define WS_MX    512
#define WS_DII   768
#define WS_NP    16640
#define WS_GP    20736
#define WS_P     4215040
#define WS_PS    6344960
#define WS_PL    6345025

#define PI_F 3.14159265358979323846f

// ---------------- Register/shuffle 128-pt complex FFT (DIF, bit-reversed out) --
__device__ __forceinline__ void fft128_reg(float& s0r, float& s0i,
                                           float& s1r, float& s1i,
                                           float cA, float sA,
                                           const float* wr, const float* wi,
                                           int lane) {
    float er = s0r + s1r, ei = s0i + s1i;
    float dr = s0r - s1r, di = s0i - s1i;
    float orr = dr * cA - di * sA;
    float oii = dr * sA + di * cA;
    #pragma unroll
    for (int st = 0; st < 6; ++st) {
        int m = 32 >> st;
        bool up = (lane & m) == 0;
        float tr = __shfl_xor(er, m), ti = __shfl_xor(ei, m);
        float ar = tr - er, ai = ti - ei;
        float e2r = up ? (er + tr) : (ar * wr[st] - ai * wi[st]);
        float e2i = up ? (ei + ti) : (ar * wi[st] + ai * wr[st]);
        tr = __shfl_xor(orr, m); ti = __shfl_xor(oii, m);
        float br_ = tr - orr, bi_ = ti - oii;
        float o2r = up ? (orr + tr) : (br_ * wr[st] - bi_ * wi[st]);
        float o2i = up ? (oii + ti) : (br_ * wi[st] + bi_ * wr[st]);
        er = e2r; ei = e2i; orr = o2r; oii = o2i;
    }
    s0r = er; s0i = ei; s1r = orr; s1i = oii;
}

// ---------------- Kernel 1: merged gram (blocks 0..255) + fft (256..511) -------
__global__ __launch_bounds__(512) void ocl_main(const float* __restrict__ x1,
                                                const float* __restrict__ x2,
                                                float* __restrict__ ws) {
    __shared__ float4 smem4[4096];     // 64 KB union
    int t = threadIdx.x;
    int bid = blockIdx.x;

    if (bid < 256) {
        // ================= GRAM K-split ks (K-chunk 64) =================
        float4* As = smem4;            // [128][16] float4, XOR-swizzled
        float4* Bs = smem4 + 2048;
        int ks = bid, k0q = ks * 16;
        const float4* A = (const float4*)x1;
        const float4* B = (const float4*)x2;
        {
            int qi = t & 15, r0 = t >> 4;
            #pragma unroll
            for (int p = 0; p < 4; ++p) {
                int r = r0 + 32 * p;
                int sq = qi ^ ((r >> 3) & 7);
                As[r * 16 + sq] = A[(size_t)r * 4096 + k0q + qi];
                Bs[r * 16 + sq] = B[(size_t)r * 4096 + k0q + qi];
            }
        }
        __syncthreads();

        int ty = t >> 4, tx = t & 15;  // rows ty*4.., col-quads tx*2..
        float acc[4][8];
        #pragma unroll
        for (int r = 0; r < 4; ++r)
            #pragma unroll
            for (int c = 0; c < 8; ++c) acc[r][c] = 0.0f;

        for (int qk = 0; qk < 16; ++qk) {
            float4 a4[4], b4[8];
            #pragma unroll
            for (int r = 0; r < 4; ++r) {
                int rr = ty * 4 + r;
                a4[r] = As[rr * 16 + (qk ^ ((rr >> 3) & 7))];
            }
            #pragma unroll
            for (int c = 0; c < 8; ++c) {
                int rc = tx * 8 + c;
                b4[c] = Bs[rc * 16 + (qk ^ ((rc >> 3) & 7))];
            }
            #pragma unroll
            for (int r = 0; r < 4; ++r)
                #pragma unroll
                for (int c = 0; c < 8; ++c) {
                    float4 a = a4[r], b = b4[c];
                    acc[r][c] = fmaf(a.x, b.x, fmaf(a.y, b.y,
                                fmaf(a.z, b.z, fmaf(a.w, b.w, acc[r][c]))));
                }
        }

        // Interleaved store: Gp4[e16*1024 + ks*4 + q], e4 = row*32 + (tx*2+cc)
        float4* Gp4 = (float4*)(ws + WS_GP);
        #pragma unroll
        for (int r = 0; r < 4; ++r)
            #pragma unroll
            for (int cc = 0; cc < 2; ++cc) {
                int e4 = (ty * 4 + r) * 32 + tx * 2 + cc;
                Gp4[(size_t)(e4 >> 2) * 1024 + ks * 4 + (e4 & 3)] =
                    make_float4(acc[r][cc * 4 + 0], acc[r][cc * 4 + 1],
                                acc[r][cc * 4 + 2], acc[r][cc * 4 + 3]);
            }
    } else {
        // ================= FFT + PSD + norm partials (no atomics) =======
        float* zre = (float*)smem4;
        float* zim = zre + 8192;
        int lane = t & 63, wave = t >> 6;   // 8 waves
        int img = bid - 256;
        const float* src = (img < 128) ? (x1 + (size_t)img * 16384)
                                       : (x2 + (size_t)(img - 128) * 16384);

        float cA, sA, wr[6], wi[6];
        {
            float th = -PI_F * (float)lane / 64.0f;
            sA = __sinf(th); cA = __cosf(th);
            #pragma unroll
            for (int st = 0; st < 6; ++st) {
                int m = 32 >> st;
                float a = -PI_F * (float)(lane & (m - 1)) / (float)m;
                wi[st] = __sinf(a); wr[st] = __cosf(a);
            }
        }
        int rb = (int)(__brev((unsigned)lane) >> 26);  // br6(lane)

        float nrm = 0.0f;
        #pragma unroll
        for (int pi = 0; pi < 8; ++pi) {
            int p = wave * 8 + pi;
            const float* r0 = src + p * 256 + lane;
            float s0r = r0[0],   s1r = r0[64];
            float s0i = r0[128], s1i = r0[192];
            nrm += s0r * s0r + s1r * s1r + s0i * s0i + s1i * s1i;
            fft128_reg(s0r, s0i, s1r, s1i, cA, sA, wr, wi, lane);
            int f0 = (2 * rb + p) & 127;
            int f1 = (2 * rb + 1 + p) & 127;
            zre[p * 128 + f0] = s0r; zim[p * 128 + f0] = s0i;
            zre[p * 128 + f1] = s1r; zim[p * 128 + f1] = s1i;
        }
        for (int off = 32; off >= 1; off >>= 1) nrm += __shfl_xor(nrm, off);
        if (lane == 0) ws[WS_NP + img * 8 + wave] = nrm;   // plain store
        __syncthreads();

        int p0 = (lane >> 1), p1 = 32 + (lane >> 1);
        int par = lane & 1;
        float* P = ws + WS_P;
        for (int k = wave; k < 65; k += 8) {
            float v0r, v0i, v1r, v1i;
            if (k == 0 || k == 64) {
                int c0 = (k + p0) & 127, c1 = (k + p1) & 127;
                float Z0r = zre[p0 * 128 + c0], Z0i = zim[p0 * 128 + c0];
                float Z1r = zre[p1 * 128 + c1], Z1i = zim[p1 * 128 + c1];
                v0r = par ? Z0i : Z0r; v0i = 0.0f;
                v1r = par ? Z1i : Z1r; v1i = 0.0f;
            } else {
                int kn = 128 - k;
                int ck = (k + p0) & 127, cn = (kn + p0) & 127;
                float Zkr = zre[p0 * 128 + ck], Zki = zim[p0 * 128 + ck];
                float Znr = zre[p0 * 128 + cn], Zni = zim[p0 * 128 + cn];
                float e0r = 0.5f * (Zkr + Znr), e0i = 0.5f * (Zki - Zni);
                float q0r = 0.5f * (Zki + Zni), q0i = 0.5f * (Znr - Zkr);
                v0r = par ? q0r : e0r; v0i = par ? q0i : e0i;
                ck = (k + p1) & 127; cn = (kn + p1) & 127;
                Zkr = zre[p1 * 128 + ck]; Zki = zim[p1 * 128 + ck];
                Znr = zre[p1 * 128 + cn]; Zni = zim[p1 * 128 + cn];
                float e1r = 0.5f * (Zkr + Znr), e1i = 0.5f * (Zki - Zni);
                float q1r = 0.5f * (Zki + Zni), q1i = 0.5f * (Znr - Zkr);
                v1r = par ? q1r : e1r; v1i = par ? q1i : e1i;
            }
            fft128_reg(v0r, v0i, v1r, v1i, cA, sA, wr, wi, lane);
            int m = lane & 15, hi = lane >> 4;
            P[(size_t)(k * 8 + 0 + hi) * 4096 + img * 16 + m] = v0r * v0r + v0i * v0i;
            P[(size_t)(k * 8 + 4 + hi) * 4096 + img * 16 + m] = v1r * v1r + v1i * v1i;
        }
    }
}

// ---------------- Kernel 2: reductions (grid 321) ------------------------------
// blocks [0,256): block g: Gp slice -> D half-row -> (Mx[g], Se[g], Dii)
// blocks [256,321): PSD bins of column k=bid-256 -> PS[k], PL[k]
__global__ __launch_bounds__(256) void ocl_finish(float* __restrict__ ws) {
    int bid = blockIdx.x, t = threadIdx.x;
    int lane = t & 63, wave = t >> 6;

    if (bid < 256) {
        int g = bid;
        const float4* Gp4 = (const float4*)(ws + WS_GP);
        int q = (lane >> 4) & 3, kg = lane & 15;
        const float4* base = Gp4 + (size_t)g * 4096 + wave * 1024 + q;
        float4 v[16];
        #pragma unroll
        for (int it = 0; it < 16; ++it) v[it] = base[(kg * 16 + it) * 4];

        // na/nb from NP partials (cooperative, LDS)
        __shared__ float nbs[64];
        __shared__ float s_na;
        __shared__ float sm[4], sm2[4];
        if (t < 64) {
            const float* np = ws + WS_NP + (size_t)(128 + (g & 1) * 64 + t) * 8;
            nbs[t] = ((np[0] + np[1]) + (np[2] + np[3])) +
                     ((np[4] + np[5]) + (np[6] + np[7]));
        }
        if (t == 64) {
            const float* np = ws + WS_NP + (size_t)(g >> 1) * 8;
            s_na = ((np[0] + np[1]) + (np[2] + np[3])) +
                   ((np[4] + np[5]) + (np[6] + np[7]));
        }

        float4 s = v[0];
        #pragma unroll
        for (int it = 1; it < 16; ++it) {
            s.x += v[it].x; s.y += v[it].y; s.z += v[it].z; s.w += v[it].w;
        }
        #pragma unroll
        for (int msk = 1; msk <= 8; msk <<= 1) {
            s.x += __shfl_xor(s.x, msk); s.y += __shfl_xor(s.y, msk);
            s.z += __shfl_xor(s.z, msk); s.w += __shfl_xor(s.w, msk);
        }
        __syncthreads();   // nbs / s_na ready

        // All lanes of a q-group compute identical d4 (values broadcast-safe).
        int cq = wave * 4 + q;           // column quad 0..15 within half-row
        float nai = s_na;
        float4 d;
        d.x = sqrtf(fmaxf(nai + nbs[cq * 4 + 0] - 2.0f * s.x, 0.0f));
        d.y = sqrtf(fmaxf(nai + nbs[cq * 4 + 1] - 2.0f * s.y, 0.0f));
        d.z = sqrtf(fmaxf(nai + nbs[cq * 4 + 2] - 2.0f * s.z, 0.0f));
        d.w = sqrtf(fmaxf(nai + nbs[cq * 4 + 3] - 2.0f * s.w, 0.0f));

        // Diagonal
        int i = g >> 1;
        int jr = i - (g & 1) * 64;
        if (kg == 0 && jr >= 0 && jr < 64 && cq == (jr >> 2)) {
            float dii = (jr & 2) ? ((jr & 1) ? d.w : d.z) : ((jr & 1) ? d.y : d.x);
            ws[WS_DII + i] = dii;
        }

        // Local max over the half-row (cross-q via shfl, cross-wave via LDS)
        float m = fmaxf(fmaxf(d.x, d.y), fmaxf(d.z, d.w));
        m = fmaxf(m, __shfl_xor(m, 16));
        m = fmaxf(m, __shfl_xor(m, 32));
        if (lane == 0) sm[wave] = m;
        __syncthreads();
        float M = fmaxf(fmaxf(sm[0], sm[1]), fmaxf(sm[2], sm[3]));

        // Sum of exp(d - M)
        float se = __expf(d.x - M) + __expf(d.y - M) +
                   __expf(d.z - M) + __expf(d.w - M);
        se += __shfl_xor(se, 16);
        se += __shfl_xor(se, 32);
        if (lane == 0) sm2[wave] = se;
        __syncthreads();
        if (t == 0) {
            ws[WS_SE + g] = sm2[0] + sm2[1] + sm2[2] + sm2[3];
            ws[WS_MX + g] = M;
        }
    } else {
        int k = bid - 256;
        const float4* P4 = (const float4*)(ws + WS_P);
        int b16 = t >> 5, m4 = (t >> 3) & 3, hq = t & 7;
        const float4* base = P4 + (size_t)(k * 8 + b16) * 1024 + m4;
        float4 s = make_float4(0.f, 0.f, 0.f, 0.f);
        #pragma unroll
        for (int half = 0; half < 2; ++half) {
            float4 u[16];
            #pragma unroll
            for (int it = 0; it < 16; ++it)
                u[it] = base[(hq * 32 + half * 16 + it) * 4];
            #pragma unroll
            for (int it = 0; it < 16; ++it) {
                s.x += u[it].x; s.y += u[it].y; s.z += u[it].z; s.w += u[it].w;
            }
        }
        #pragma unroll
        for (int msk = 1; msk <= 4; msk <<= 1) {
            s.x += __shfl_xor(s.x, msk); s.y += __shfl_xor(s.y, msk);
            s.z += __shfl_xor(s.z, msk); s.w += __shfl_xor(s.w, msk);
        }
        float sS = 0.0f, sL = 0.0f;
        if (hq == 0) {
            float w = (k == 0 || k == 64) ? 1.0f : 2.0f;
            sS = w * (s.x + s.y + s.z + s.w);
            sL = w * (logf(s.x) + logf(s.y) + logf(s.z) + logf(s.w));
        }
        #pragma unroll
        for (int off = 32; off >= 1; off >>= 1) {
            sS += __shfl_xor(sS, off);
            sL += __shfl_xor(sL, off);
        }
        __shared__ float aS[4], aL[4];
        if (lane == 0) { aS[wave] = sS; aL[wave] = sL; }
        __syncthreads();
        if (t == 0) {
            ws[WS_PS + k] = aS[0] + aS[1] + aS[2] + aS[3];
            ws[WS_PL + k] = aL[0] + aL[1] + aL[2] + aL[3];
        }
    }
}

// ---------------- Kernel 3: tail — merge half-row LSE partials + PSD -> scalar -
__global__ __launch_bounds__(256) void ocl_tail(const float* __restrict__ ws,
                                                float* __restrict__ out) {
    int t = threadIdx.x, lane = t & 63, wave = t >> 6;

    float rowacc = 0.0f;
    if (t < 128) {
        int i = t;
        float sea = ws[WS_SE + 2 * i],     seb = ws[WS_SE + 2 * i + 1];
        float ma  = ws[WS_MX + 2 * i],     mb  = ws[WS_MX + 2 * i + 1];
        float dii = ws[WS_DII + i];
        float M = fmaxf(ma, mb);
        float se = sea * __expf(ma - M) + seb * __expf(mb - M);
        rowacc = M + logf(se) - dii;
    }

    float sS = 0.0f, sL = 0.0f;
    if (t < 65) { sS = ws[WS_PS + t]; sL = ws[WS_PL + t]; }
    #pragma unroll
    for (int off = 32; off >= 1; off >>= 1) {
        sS += __shfl_xor(sS, off);
        sL += __shfl_xor(sL, off);
        rowacc += __shfl_xor(rowacc, off);
    }
    __shared__ float bS[4], bL[4], bR[4];
    if (lane == 0) { bS[wave] = sS; bL[wave] = sL; bR[wave] = rowacc; }
    __syncthreads();
    if (t == 0) {
        float S_ = bS[0] + bS[1] + bS[2] + bS[3];
        float L_ = bL[0] + bL[1] + bL[2] + bL[3];
        float R_ = bR[0] + bR[1] + bR[2] + bR[3];
        float ce = R_ / 128.0f;
        float r  = L_ / 16384.0f - logf(S_ / 16384.0f);
        out[0] = ce - 0.1f * r;
    }
}

extern "C" void kernel_launch(void* const* d_in, const int* in_sizes, int n_in,
                              void* d_out, int out_size, void* d_ws, size_t ws_size,
                              hipStream_t stream) {
    (void)in_sizes; (void)n_in; (void)out_size; (void)ws_size;
    const float* x1 = (const float*)d_in[0];
    const float* x2 = (const float*)d_in[1];
    float* ws  = (float*)d_ws;
    float* out = (float*)d_out;

    hipLaunchKernelGGL(ocl_main,   dim3(512), dim3(512), 0, stream, x1, x2, ws);
    hipLaunchKernelGGL(ocl_finish, dim3(321), dim3(256), 0, stream, ws);
    hipLaunchKernelGGL(ocl_tail,   dim3(1),   dim3(256), 0, stream, ws, out);
}